// Round 8
// baseline (304.215 us; speedup 1.0000x reference)
//
#include <hip/hip_runtime.h>
#include <stdint.h>

typedef __attribute__((ext_vector_type(8))) __bf16 bf16x8;
typedef __attribute__((ext_vector_type(4))) short short4v;
typedef __attribute__((ext_vector_type(4))) float f32x4;

#if __has_builtin(__builtin_amdgcn_exp2f)
#define EXP2(x) __builtin_amdgcn_exp2f(x)
#else
#define EXP2(x) exp2f(x)
#endif

// ---------- helpers ----------
__device__ __forceinline__ short f2bf(float f) {
  union { float f; uint32_t u; } v; v.f = f;
  uint32_t r = (v.u + 0x7fffu + ((v.u >> 16) & 1u)) >> 16;  // RNE
  return (short)(uint16_t)r;
}

// pack two fp32 -> two bf16 in one dword (RNE via hw bf16 cvt)
__device__ __forceinline__ uint32_t pk2bf(float a, float b) {
  union { __bf16 h; uint16_t u; } x, y;
  x.h = (__bf16)a; y.h = (__bf16)b;
  return (uint32_t)x.u | ((uint32_t)y.u << 16);
}

// async global->LDS, 16B per lane; lds base must be wave-uniform, HW writes lane i at base+16*i
__device__ __forceinline__ void gl2lds16(const void* g, const void* lds) {
  __builtin_amdgcn_global_load_lds(
      (const __attribute__((address_space(1))) void*)(uintptr_t)g,
      (__attribute__((address_space(3))) void*)(uint32_t)(uintptr_t)lds,
      16, 0, 0);
}

__device__ __forceinline__ bf16x8 frag8(const short* p) {
  return *(const bf16x8*)(const void*)p;
}

// ---------- kernel 1: fp32 -> bf16 for x, W_qkv, W_out ----------
__global__ void convert3_k(const float* __restrict__ s0, short* __restrict__ d0, int n0,
                           const float* __restrict__ s1, short* __restrict__ d1, int n1,
                           const float* __restrict__ s2, short* __restrict__ d2, int n2) {
  int i = blockIdx.x * blockDim.x + threadIdx.x;  // float4 units
  int t0 = n0 >> 2, t1 = t0 + (n1 >> 2), t2 = t1 + (n2 >> 2);
  const float* s; short* d; int off;
  if (i < t0) { s = s0; d = d0; off = i; }
  else if (i < t1) { s = s1; d = d1; off = i - t0; }
  else if (i < t2) { s = s2; d = d2; off = i - t1; }
  else return;
  float4 v = ((const float4*)s)[off];
  short4v o;
  o.x = f2bf(v.x); o.y = f2bf(v.y); o.z = f2bf(v.z); o.w = f2bf(v.w);
  *(short4v*)(d + off * 4) = o;
}

// ---------- kernel 2: RoPE tables TRANSPOSED [j=32][pos=2048] + float mask table ----------
__global__ void rope_tab_k(float* __restrict__ cosT, float* __restrict__ sinT,
                           const unsigned char* __restrict__ mask, float* __restrict__ maskf) {
  int i = blockIdx.x * blockDim.x + threadIdx.x;  // 65536
  int j = i >> 11, pos = i & 2047;
  float invf = exp2f(-(float)j * (8.965784284662087f / 32.0f));
  float ang = (float)pos * invf;
  float s, c;
  sincosf(ang, &s, &c);
  cosT[i] = c; sinT[i] = s;
  if (i < 8192) maskf[i] = mask[i] ? -1e30f : 0.0f;
}

// ---------- kernel 3: 256x256 8-phase-style GEMM (gemm1), C = A * B^T + bias ----------
// BM=BN=256, BK=64, 512 threads = 8 waves (2M x 4N), per-wave C = 128x64 (acc[8][4]).
// LDS: 2 buffers x [256][64] bf16 per matrix = 128KB. Rows 128B = 8 x 16B chunks,
// XOR-swizzled chunk' = chunk ^ (row&7); staged via pre-swizzled global source (linear LDS
// dest, both-sides rule). 16 K-tiles; tile t lives in buffer t&1.
// Schedule per tile = 4 phases; phase q: {phase0 only: issue ALL 8 prefetch gl2lds for tile
// t+1 into buffer (t+1)&1 + read 8 B-frags} + read 4 A-frags (quadrant q) -> barrier ->
// setprio(1) 16 MFMA setprio(0) -> [q==3: s_waitcnt vmcnt(0) -- issued 4 phases (~1000cyc)
// earlier so effectively free] -> barrier.
// Race-safety: prefetch never targets the compute buffer; buffer (t+1)&1 was last read at
// tile t-1, whose reads completed before tile t-1's closing barrier; the closing
// vmcnt-before-barrier publishes staging to all waves before tile t+1's phase-0 reads.
// EPI==1: bias + RoPE + scatter Qb/Kb (bh,pos,d) and Vt (bh,d,pos); each wave's 64 cols =
// exactly one head (col0 is 64-aligned; sector/head wave-uniform). Q scaled by 0.125*log2e.
template <int EPI>
__global__ __launch_bounds__(512, 2)
void gemm256_k(const short* __restrict__ A, const short* __restrict__ Bm,
               const float* __restrict__ bias, int N, int K,
               float* __restrict__ Cout,
               const float* __restrict__ cosT, const float* __restrict__ sinT,
               short* __restrict__ Qb, short* __restrict__ Kb, short* __restrict__ Vt) {
  __shared__ short As[2][256 * 64];
  __shared__ short Bs[2][256 * 64];
  const int tid = threadIdx.x;
  const int lane = tid & 63;
  const int w = tid >> 6;            // 0..7
  const int wr = w >> 2, wc = w & 3; // 2M x 4N wave grid
  const int g = lane >> 4, l15 = lane & 15;

  // XCD mapping (384 blocks): XCD = bid&7 owns bm-slice [4k,4k+4) x all 12 bn
  // (A 4x512KB = 2MB L2-resident per XCD; B streamed -- the proven-good direction).
  int bm, bn;
  if (EPI == 1) {
    const int swz = (blockIdx.x & 7) * 48 + (blockIdx.x >> 3);
    bm = swz / 12; bn = swz % 12;
  } else {
    bm = blockIdx.x; bn = blockIdx.y;
  }
  const int rowA0 = bm * 256;
  const int rowB0 = bn * 256;

  // staging terms: 8KB set = 64 rows x 128B; thread covers 16B at (row=tid>>3, chunk=tid&7)
  const int rl = tid >> 3;
  const int cl = tid & 7;
  const int sc8 = (cl ^ (rl & 7)) * 8;  // pre-swizzled source element offset in row
  const int ldso = w * 512;             // wave slice (shorts) within an 8KB set
  const int swz7 = l15 & 7;             // read-side swizzle

  f32x4 acc[8][4];
#pragma unroll
  for (int i = 0; i < 8; i++)
#pragma unroll
    for (int j = 0; j < 4; j++) acc[i][j] = f32x4{0.f, 0.f, 0.f, 0.f};

  auto stageT = [&](int kt) {
    short* dA = &As[kt & 1][0];
    short* dB = &Bs[kt & 1][0];
#pragma unroll
    for (int hh = 0; hh < 2; ++hh)
#pragma unroll
      for (int s = 0; s < 2; ++s) {
        const int r = hh * 128 + s * 64 + rl;
        const int ld = (hh * 128 + s * 64) * 64 + ldso;
        gl2lds16(A + (rowA0 + r) * K + kt * 64 + sc8, dA + ld);
        gl2lds16(Bm + (rowB0 + r) * K + kt * 64 + sc8, dB + ld);
      }
  };

  // prologue: stage tile 0 into buffer 0
  stageT(0);
  asm volatile("s_waitcnt vmcnt(0)" ::: "memory");
  __builtin_amdgcn_s_barrier();

  for (int t = 0; t < 16; ++t) {
    const short* as = &As[t & 1][0];
    const short* bs = &Bs[t & 1][0];
    bf16x8 bfr[4][2];
#pragma unroll
    for (int q = 0; q < 4; ++q) {
      if (q == 0) {
        if (t + 1 < 16) stageT(t + 1);  // 8 issues, consumed next tile (>=4 phases cover)
#pragma unroll
        for (int j = 0; j < 4; ++j)
#pragma unroll
          for (int kk = 0; kk < 2; ++kk)
            bfr[j][kk] = frag8(&bs[(wc * 64 + j * 16 + l15) * 64 + (((kk * 4 + g) ^ swz7) * 8)]);
      }
      bf16x8 afr[2][2];
#pragma unroll
      for (int ii = 0; ii < 2; ++ii)
#pragma unroll
        for (int kk = 0; kk < 2; ++kk)
          afr[ii][kk] = frag8(&as[(wr * 128 + (q * 2 + ii) * 16 + l15) * 64 + (((kk * 4 + g) ^ swz7) * 8)]);
      __builtin_amdgcn_s_barrier();
      __builtin_amdgcn_s_setprio(1);
#pragma unroll
      for (int ii = 0; ii < 2; ++ii)
#pragma unroll
        for (int j = 0; j < 4; ++j)
#pragma unroll
          for (int kk = 0; kk < 2; ++kk)
            acc[q * 2 + ii][j] =
                __builtin_amdgcn_mfma_f32_16x16x32_bf16(afr[ii][kk], bfr[j][kk], acc[q * 2 + ii][j], 0, 0, 0);
      __builtin_amdgcn_s_setprio(0);
      if (q == 3) asm volatile("s_waitcnt vmcnt(0)" ::: "memory");  // drains ~free (issued 4 phases ago)
      __builtin_amdgcn_s_barrier();
    }
  }

  const int row0 = rowA0 + wr * 128 + g * 4;  // + i*16 + r
  const int col0 = rowB0 + wc * 64;           // + j*16 + l15

  if (EPI == 0) {
#pragma unroll
    for (int j = 0; j < 4; ++j) {
      float bb = bias[col0 + j * 16 + l15];
#pragma unroll
      for (int i = 0; i < 8; ++i)
#pragma unroll
        for (int r = 0; r < 4; ++r) {
          int row = row0 + i * 16 + r;
          Cout[row * N + col0 + j * 16 + l15] = acc[i][j][r] + bb;
        }
    }
  } else {
#pragma unroll
    for (int j = 0; j < 4; ++j) {
      float bb = bias[col0 + j * 16 + l15];
#pragma unroll
      for (int i = 0; i < 8; ++i)
#pragma unroll
        for (int r = 0; r < 4; ++r) acc[i][j][r] += bb;
    }
    const int sector = col0 >> 10;        // 0=q 1=k 2=v, wave-uniform
    const int h = (col0 & 1023) >> 6;     // wave-uniform head
    const int posb = row0 & 2047;         // blocks never cross a batch (2048 % 256 == 0)
    const int bq = row0 >> 11;
    if (sector == 2) {
      // V^T scatter, vectorized along pos
#pragma unroll
      for (int j = 0; j < 4; ++j) {
        int d = j * 16 + l15;
#pragma unroll
        for (int i = 0; i < 8; ++i) {
          int pos = posb + i * 16;
          union { uint32_t u[2]; short4v s4; } pw;
          pw.u[0] = pk2bf(acc[i][j][0], acc[i][j][1]);
          pw.u[1] = pk2bf(acc[i][j][2], acc[i][j][3]);
          *(short4v*)&Vt[((bq * 16 + h) * 64 + d) * 2048 + pos] = pw.s4;
        }
      }
    } else {
      short* dst = (sector == 0) ? Qb : Kb;
      const float scl = (sector == 0) ? 0.18033688011112042f : 1.0f;  // 0.125*log2(e) folded into Q
#pragma unroll
      for (int j = 0; j < 4; ++j) {
        int d = j * 16 + l15;
        int jj = d & 31;
        const float* cp = cosT + jj * 2048;
        const float* sp = sinT + jj * 2048;
#pragma unroll
        for (int i = 0; i < 8; ++i) {
          f32x4 cv = *(const f32x4*)(cp + posb + i * 16);
          f32x4 sn = *(const f32x4*)(sp + posb + i * 16);
#pragma unroll
          for (int r = 0; r < 4; ++r) {
            int pos = posb + i * 16 + r;
            float xv = acc[i][j][r];
            float xp = acc[i][j ^ 2][r];           // partner d +/- 32 lives 2 n-reps away
            float rot = (j < 2) ? -xp : xp;        // d<32: -x[d+32]; d>=32: x[d-32]
            dst[((bq * 16 + h) * 2048 + pos) * 64 + d] = f2bf((xv * cv[r] + rot * sn[r]) * scl);
          }
        }
      }
    }
  }
}

// ---------- kernel 3b/5: 128x128 tri-buffer GEMM (gemm2 / output proj) ----------
// TRI-buffered LDS staging + raw s_barrier + counted vmcnt (proven): prefetch distance 2
// tiles, 4 gl2lds16/iter, s_waitcnt vmcnt(4) before the barrier. LDS 48KB -> 3 blocks/CU.
template <int EPI>
__global__ __launch_bounds__(256, 3)
void gemm_bt_k(const short* __restrict__ A, const short* __restrict__ Bm,
               const float* __restrict__ bias, int N, int K,
               float* __restrict__ Cout) {
  __shared__ short As[3][128 * 32];
  __shared__ short Bs[3][128 * 32];
  const int tid = threadIdx.x;
  const int lane = tid & 63;
  const int w = tid >> 6;
  const int g = lane >> 4, l15 = lane & 15;
  const int wm = (w >> 1) * 64, wn = (w & 1) * 64;
  const int bm = blockIdx.x, bn = blockIdx.y;

  const int rseg = lane >> 2;
  const int cofs = ((lane & 3) ^ ((lane >> 3) & 3)) * 8;
  const int sA0 = w, sA1 = w + 4;
  const int arow0 = (bm * 128 + sA0 * 16 + rseg) * K;
  const int arow1 = (bm * 128 + sA1 * 16 + rseg) * K;
  const int brow0 = (bn * 128 + sA0 * 16 + rseg) * K;
  const int brow1 = (bn * 128 + sA1 * 16 + rseg) * K;

  const int rsw = (l15 >> 1) & 3;  // read-side swizzle term

  f32x4 acc[4][4];
#pragma unroll
  for (int i = 0; i < 4; i++)
#pragma unroll
    for (int j = 0; j < 4; j++) acc[i][j] = f32x4{0.f, 0.f, 0.f, 0.f};

#pragma unroll
  for (int t = 0; t < 2; t++) {
    gl2lds16(A + arow0 + t * 32 + cofs, &As[t][sA0 * 512]);
    gl2lds16(A + arow1 + t * 32 + cofs, &As[t][sA1 * 512]);
    gl2lds16(Bm + brow0 + t * 32 + cofs, &Bs[t][sA0 * 512]);
    gl2lds16(Bm + brow1 + t * 32 + cofs, &Bs[t][sA1 * 512]);
  }

  const int K32 = K >> 5;
  int cur = 0, pre = 2;
  for (int kt = 0; kt < K32; kt++) {
    if (kt < K32 - 1) { asm volatile("s_waitcnt vmcnt(4)" ::: "memory"); }
    else              { asm volatile("s_waitcnt vmcnt(0)" ::: "memory"); }
    __builtin_amdgcn_s_barrier();

    if (kt + 2 < K32) {
      const int k2 = (kt + 2) * 32;
      gl2lds16(A + arow0 + k2 + cofs, &As[pre][sA0 * 512]);
      gl2lds16(A + arow1 + k2 + cofs, &As[pre][sA1 * 512]);
      gl2lds16(Bm + brow0 + k2 + cofs, &Bs[pre][sA0 * 512]);
      gl2lds16(Bm + brow1 + k2 + cofs, &Bs[pre][sA1 * 512]);
    }
    bf16x8 af[4], bf[4];
#pragma unroll
    for (int im = 0; im < 4; im++) af[im] = frag8(&As[cur][(wm + im * 16 + l15) * 32 + (g ^ rsw) * 8]);
#pragma unroll
    for (int jn = 0; jn < 4; jn++) bf[jn] = frag8(&Bs[cur][(wn + jn * 16 + l15) * 32 + (g ^ rsw) * 8]);
#pragma unroll
    for (int im = 0; im < 4; im++)
#pragma unroll
      for (int jn = 0; jn < 4; jn++)
        acc[im][jn] = __builtin_amdgcn_mfma_f32_16x16x32_bf16(af[im], bf[jn], acc[im][jn], 0, 0, 0);

    cur = (cur == 2) ? 0 : cur + 1;
    pre = (pre == 2) ? 0 : pre + 1;
  }

  const int row0 = bm * 128 + wm + g * 4;
  const int col0 = bn * 128 + wn;
#pragma unroll
  for (int jn = 0; jn < 4; jn++) {
    float bb = bias[col0 + jn * 16 + l15];
#pragma unroll
    for (int im = 0; im < 4; im++)
#pragma unroll
      for (int r = 0; r < 4; r++) {
        int row = row0 + im * 16 + r;
        Cout[row * N + col0 + jn * 16 + l15] = acc[im][jn][r] + bb;
      }
  }
}

// ---------- kernel 4: attention (measured best ~95.6us) ----------
// 256-thread blocks (4 waves), q=128/block (32/wave), kv-tile=32, TRI-buffered staging.
// Grid 1024 (16 qt x 64 bh, XCD-swizzled so XCD k owns bh in [8k,8k+8) -> 4MB K/V = L2-resident).
// 4 blocks/CU at 40KB LDS -> 16 waves/CU.
// Waves 0,1 stage K, waves 2,3 stage V^T; mask in LDS (staged once); loop body issues EXACTLY
// 2 VMEM ops/iter -> counted s_waitcnt vmcnt(2) keeps next tile's loads in flight across the
// raw s_barrier (prefetch distance = 2 iters).
// DEFERRED-PV (T15): iteration t issues PV for tile t-1 from register snapshots (av, bp).
// p = exp2(s + maskf) unnormalized (Q pre-scaled by 0.125*log2e); l via ones-MFMA.
__global__ __launch_bounds__(256, 4)
void attn_k(const short* __restrict__ Qb, const short* __restrict__ Kb,
            const short* __restrict__ Vt, const float* __restrict__ maskf,
            short* __restrict__ attn) {
  __shared__ short Ks[3][32 * 64];  // [kv][d]   rows 128B = 8 chunks, pos = c ^ (row&7)
  __shared__ short Vs[3][64 * 32];  // [d][kv]   rows  64B = 4 chunks, pos = c ^ ((row^(row>>2))&3)
  __shared__ short Ps[4][32 * 32];  // per-wave [q][kv] rows 64B, same 4-chunk swizzle
  __shared__ float Ms[2048];        // this batch's mask row (adds), staged once
  const int tid = threadIdx.x, lane = tid & 63, w = tid >> 6;
  const int g = lane >> 4, l15 = lane & 15;
  const int swk = l15 & 7;                    // Ks read swizzle
  const int fv = (l15 ^ (l15 >> 2)) & 3;      // Vs/Ps read swizzle
  const int swz = (blockIdx.x & 7) * 128 + (blockIdx.x >> 3);
  const int qt = swz & 15, bh = swz >> 4;
  const int b = bh >> 4, h = bh & 15;

  bf16x8 aq[2][2];
#pragma unroll
  for (int qi = 0; qi < 2; qi++)
#pragma unroll
    for (int kc = 0; kc < 2; kc++) {
      int q = qt * 128 + w * 32 + qi * 16 + l15;
      aq[qi][kc] = *(const bf16x8*)(const void*)(Qb + (bh * 2048 + q) * 64 + kc * 32 + g * 8);
    }
  bf16x8 aone;
#pragma unroll
  for (int i = 0; i < 8; i++) aone[i] = (__bf16)1.0f;

  f32x4 o[4][2];
#pragma unroll
  for (int jd = 0; jd < 4; jd++)
#pragma unroll
    for (int qi = 0; qi < 2; qi++) o[jd][qi] = f32x4{0.f, 0.f, 0.f, 0.f};
  f32x4 lacc[2] = {f32x4{0.f, 0.f, 0.f, 0.f}, f32x4{0.f, 0.f, 0.f, 0.f}};

  bf16x8 av[4], bp[2];
#pragma unroll
  for (int jd = 0; jd < 4; jd++)
#pragma unroll
    for (int i = 0; i < 8; i++) av[jd][i] = (__bf16)0.0f;
#pragma unroll
  for (int qi = 0; qi < 2; qi++)
#pragma unroll
    for (int i = 0; i < 8; i++) bp[qi][i] = (__bf16)0.0f;

  const float* mfp = maskf + b * 2048;

  const int kr8 = lane >> 3;
  const int kcst = (lane & 7) ^ kr8;
  const int vrs = lane >> 2;
  const int vcs = (lane & 3) ^ ((vrs ^ (vrs >> 2)) & 3);

#pragma unroll
  for (int i = 0; i < 2; i++) {
    int s = w * 2 + i;
    gl2lds16(mfp + s * 256 + lane * 4, &Ms[s * 256]);
  }
  if (w < 2) {
#pragma unroll
    for (int t = 0; t < 2; t++)
#pragma unroll
      for (int i = 0; i < 2; i++) {
        int s = (w & 1) * 2 + i;
        gl2lds16(Kb + (bh * 2048 + t * 32 + s * 8 + kr8) * 64 + kcst * 8, &Ks[t][s * 512]);
      }
  } else {
#pragma unroll
    for (int t = 0; t < 2; t++)
#pragma unroll
      for (int i = 0; i < 2; i++) {
        int s = (w & 1) * 2 + i;
        gl2lds16(Vt + (bh * 64 + s * 16 + vrs) * 2048 + t * 32 + vcs * 8, &Vs[t][s * 512]);
      }
  }

  int cur = 0, pre = 2;
  for (int kt = 0; kt < 64; kt++) {
    if (kt < 62) {
      asm volatile("s_waitcnt vmcnt(2)" ::: "memory");
    } else {
      asm volatile("s_waitcnt vmcnt(0)" ::: "memory");
    }
    __builtin_amdgcn_s_barrier();

    if (kt < 62) {
      const int nb = (kt + 2) * 32;
      if (w < 2) {
#pragma unroll
        for (int i = 0; i < 2; i++) {
          int s = (w & 1) * 2 + i;
          gl2lds16(Kb + (bh * 2048 + nb + s * 8 + kr8) * 64 + kcst * 8, &Ks[pre][s * 512]);
        }
      } else {
#pragma unroll
        for (int i = 0; i < 2; i++) {
          int s = (w & 1) * 2 + i;
          gl2lds16(Vt + (bh * 64 + s * 16 + vrs) * 2048 + nb + vcs * 8, &Vs[pre][s * 512]);
        }
      }
    }

    __builtin_amdgcn_s_setprio(1);
#pragma unroll
    for (int qi = 0; qi < 2; qi++) {
#pragma unroll
      for (int jd = 0; jd < 4; jd++)
        o[jd][qi] = __builtin_amdgcn_mfma_f32_16x16x32_bf16(av[jd], bp[qi], o[jd][qi], 0, 0, 0);
      lacc[qi] = __builtin_amdgcn_mfma_f32_16x16x32_bf16(aone, bp[qi], lacc[qi], 0, 0, 0);
    }
    __builtin_amdgcn_s_setprio(0);

    const int kbase = kt * 32;
    f32x4 sv[2][2];
#pragma unroll
    for (int kvt = 0; kvt < 2; kvt++) {
      f32x4 mf = *(const f32x4*)(const void*)&Ms[kbase + kvt * 16 + g * 4];
      sv[kvt][0] = mf; sv[kvt][1] = mf;
    }
    __builtin_amdgcn_s_setprio(1);
#pragma unroll
    for (int kvt = 0; kvt < 2; kvt++)
#pragma unroll
      for (int kc = 0; kc < 2; kc++) {
        bf16x8 ak = frag8(&Ks[cur][(kvt * 16 + l15) * 64 + ((kc * 4 + g) ^ swk) * 8]);
        sv[kvt][0] = __builtin_amdgcn_mfma_f32_16x16x32_bf16(ak, aq[0][kc], sv[kvt][0], 0, 0, 0);
        sv[kvt][1] = __builtin_amdgcn_mfma_f32_16x16x32_bf16(ak, aq[1][kc], sv[kvt][1], 0, 0, 0);
      }
    __builtin_amdgcn_s_setprio(0);

#pragma unroll
    for (int jd = 0; jd < 4; jd++)
      av[jd] = frag8(&Vs[cur][(jd * 16 + l15) * 32 + (g ^ fv) * 8]);

#pragma unroll
    for (int qi = 0; qi < 2; qi++)
#pragma unroll
      for (int kvt = 0; kvt < 2; kvt++) {
        union { uint32_t u[2]; short4v s4; } pw;
        pw.u[0] = pk2bf(EXP2(sv[kvt][qi][0]), EXP2(sv[kvt][qi][1]));
        pw.u[1] = pk2bf(EXP2(sv[kvt][qi][2]), EXP2(sv[kvt][qi][3]));
        *(short4v*)&Ps[w][(qi * 16 + l15) * 32 + (((kvt * 2 + (g >> 1)) ^ fv) * 8) + (g & 1) * 4] = pw.s4;
      }
#pragma unroll
    for (int qi = 0; qi < 2; qi++)
      bp[qi] = frag8(&Ps[w][(qi * 16 + l15) * 32 + (g ^ fv) * 8]);

    cur = (cur == 2) ? 0 : cur + 1;
    pre = (pre == 2) ? 0 : pre + 1;
  }

  __builtin_amdgcn_s_setprio(1);
#pragma unroll
  for (int qi = 0; qi < 2; qi++) {
#pragma unroll
    for (int jd = 0; jd < 4; jd++)
      o[jd][qi] = __builtin_amdgcn_mfma_f32_16x16x32_bf16(av[jd], bp[qi], o[jd][qi], 0, 0, 0);
    lacc[qi] = __builtin_amdgcn_mfma_f32_16x16x32_bf16(aone, bp[qi], lacc[qi], 0, 0, 0);
  }
  __builtin_amdgcn_s_setprio(0);

#pragma unroll
  for (int qi = 0; qi < 2; qi++) {
    float inv = 1.0f / lacc[qi][0];
    int q = qt * 128 + w * 32 + qi * 16 + l15;
#pragma unroll
    for (int jd = 0; jd < 4; jd++) {
      union { uint32_t u[2]; short4v s4; } pw;
      pw.u[0] = pk2bf(o[jd][qi][0] * inv, o[jd][qi][1] * inv);
      pw.u[1] = pk2bf(o[jd][qi][2] * inv, o[jd][qi][3] * inv);
      *(short4v*)&attn[(b * 2048 + q) * 1024 + h * 64 + jd * 16 + g * 4] = pw.s4;
    }
  }
}

// ---------- launch ----------
extern "C" void kernel_launch(void* const* d_in, const int* in_sizes, int n_in,
                              void* d_out, int out_size, void* d_ws, size_t ws_size,
                              hipStream_t stream) {
  const float* x = (const float*)d_in[0];
  const unsigned char* mask = (const unsigned char*)d_in[1];
  const float* W_qkv = (const float*)d_in[2];
  const float* b_qkv = (const float*)d_in[3];
  const float* W_out = (const float*)d_in[4];
  const float* b_out = (const float*)d_in[5];
  float* out = (float*)d_out;

  char* ws = (char*)d_ws;
  short* xb    = (short*)(ws + 0);          // 16,777,216 B
  short* wqkvb = (short*)(ws + 16777216);   //  6,291,456 B
  short* woutb = (short*)(ws + 23068672);   //  2,097,152 B
  float* cosT  = (float*)(ws + 25165824);   //    262,144 B  [j=32][pos=2048]
  float* sinT  = (float*)(ws + 25427968);   //    262,144 B  [j=32][pos=2048]
  short* Qb    = (short*)(ws + 25690112);   // 16,777,216 B  [bh][pos][64]
  short* Kb    = (short*)(ws + 42467328);   // 16,777,216 B  [bh][pos][64]
  short* Vtb   = (short*)(ws + 59244544);   // 16,777,216 B  [bh][64][pos]
  short* attnb = (short*)(ws + 76021760);   // 16,777,216 B  [B,L,D] bf16
  float* maskf = (float*)(ws + 92798976);   //     32,768 B

  convert3_k<<<12288, 256, 0, stream>>>(x, xb, 8388608, W_qkv, wqkvb, 3145728, W_out, woutb, 1048576);
  rope_tab_k<<<256, 256, 0, stream>>>(cosT, sinT, mask, maskf);
  gemm256_k<1><<<dim3(384), 512, 0, stream>>>(xb, wqkvb, b_qkv, 3072, 1024,
                                              nullptr, cosT, sinT, Qb, Kb, Vtb);
  attn_k<<<dim3(1024), 256, 0, stream>>>(Qb, Kb, Vtb, maskf, attnb);
  gemm_bt_k<0><<<dim3(64, 8), 256, 0, stream>>>(attnb, woutb, b_out, 1024, 1024, out);
}

// Round 9
// 279.877 us; speedup vs baseline: 1.0870x; 1.0870x over previous
//
#include <hip/hip_runtime.h>
#include <stdint.h>

typedef __attribute__((ext_vector_type(8))) __bf16 bf16x8;
typedef __attribute__((ext_vector_type(4))) short short4v;
typedef __attribute__((ext_vector_type(4))) float f32x4;

#if __has_builtin(__builtin_amdgcn_exp2f)
#define EXP2(x) __builtin_amdgcn_exp2f(x)
#else
#define EXP2(x) exp2f(x)
#endif

// ---------- helpers ----------
__device__ __forceinline__ short f2bf(float f) {
  union { float f; uint32_t u; } v; v.f = f;
  uint32_t r = (v.u + 0x7fffu + ((v.u >> 16) & 1u)) >> 16;  // RNE
  return (short)(uint16_t)r;
}

// pack two fp32 -> two bf16 in one dword (RNE via hw bf16 cvt)
__device__ __forceinline__ uint32_t pk2bf(float a, float b) {
  union { __bf16 h; uint16_t u; } x, y;
  x.h = (__bf16)a; y.h = (__bf16)b;
  return (uint32_t)x.u | ((uint32_t)y.u << 16);
}

// async global->LDS, 16B per lane; lds base must be wave-uniform, HW writes lane i at base+16*i
__device__ __forceinline__ void gl2lds16(const void* g, const void* lds) {
  __builtin_amdgcn_global_load_lds(
      (const __attribute__((address_space(1))) void*)(uintptr_t)g,
      (__attribute__((address_space(3))) void*)(uint32_t)(uintptr_t)lds,
      16, 0, 0);
}

__device__ __forceinline__ bf16x8 frag8(const short* p) {
  return *(const bf16x8*)(const void*)p;
}

// ---------- kernel 1: fp32 -> bf16 for x, W_qkv, W_out  +  fused RoPE/mask tables ----------
// Blocks [0, 12288): bf16 conversion (1 float4/thread).
// Blocks [12288, 12544): RoPE tables TRANSPOSED [j=32][pos=2048] + float mask table
// ([j][pos] layout lets the GEMM epilogue load cos/sin as float4 along pos).
__global__ void convert3_k(const float* __restrict__ s0, short* __restrict__ d0, int n0,
                           const float* __restrict__ s1, short* __restrict__ d1, int n1,
                           const float* __restrict__ s2, short* __restrict__ d2, int n2,
                           float* __restrict__ cosT, float* __restrict__ sinT,
                           const unsigned char* __restrict__ mask, float* __restrict__ maskf) {
  int i = blockIdx.x * blockDim.x + threadIdx.x;  // float4 units
  int t0 = n0 >> 2, t1 = t0 + (n1 >> 2), t2 = t1 + (n2 >> 2);
  if (i >= t2) {
    int ir = i - t2;                 // 0..65535
    if (ir < 65536) {
      int j = ir >> 11, pos = ir & 2047;
      float invf = exp2f(-(float)j * (8.965784284662087f / 32.0f));
      float ang = (float)pos * invf;
      float s, c;
      sincosf(ang, &s, &c);
      cosT[ir] = c; sinT[ir] = s;
      if (ir < 8192) maskf[ir] = mask[ir] ? -1e30f : 0.0f;
    }
    return;
  }
  const float* s; short* d; int off;
  if (i < t0) { s = s0; d = d0; off = i; }
  else if (i < t1) { s = s1; d = d1; off = i - t0; }
  else { s = s2; d = d2; off = i - t1; }
  float4 v = ((const float4*)s)[off];
  short4v o;
  o.x = f2bf(v.x); o.y = f2bf(v.y); o.z = f2bf(v.z); o.w = f2bf(v.w);
  *(short4v*)(d + off * 4) = o;
}

// ---------- kernel 3/5: C[M,N] = A[M,K] * B[N,K]^T (+bias), bf16 in, MFMA ----------
// TRI-buffered LDS staging + raw s_barrier + counted vmcnt: prefetch distance = 2 tiles;
// per iter exactly 4 gl2lds16 ops -> s_waitcnt vmcnt(4) before the barrier guarantees tile
// kt is staged while tile kt+1's 4 ops stay in flight across the barrier. vmcnt(0) last iter.
// LDS 48KB/block -> 3 blocks/CU. Rows 64B = 4x16B chunks, XOR-swizzled.
// Grid (NBM, NBN): XCD = bm%8 -> per-XCD A-slice 2MB L2-resident (A is the big operand;
// R7 measured the transposed mapping at -13us: A-resident wins).
// EPI==0: fp32 C + bias.  EPI==1: bias + RoPE + scatter Qb/Kb (bh,pos,d) and Vt (bh,d,pos).
// RoPE cos/sin loaded as float4 from the transposed [j][pos] tables (r = pos-contiguous).
// Q additionally scaled by 0.125*log2(e) so attention scores are ready for exp2.
template <int EPI>
__global__ __launch_bounds__(256, 3)
void gemm_bt_k(const short* __restrict__ A, const short* __restrict__ Bm,
               const float* __restrict__ bias, int N, int K,
               float* __restrict__ Cout,
               const float* __restrict__ cosT, const float* __restrict__ sinT,
               short* __restrict__ Qb, short* __restrict__ Kb, short* __restrict__ Vt) {
  __shared__ short As[3][128 * 32];
  __shared__ short Bs[3][128 * 32];
  const int tid = threadIdx.x;
  const int lane = tid & 63;
  const int w = tid >> 6;
  const int g = lane >> 4, l15 = lane & 15;
  const int wm = (w >> 1) * 64, wn = (w & 1) * 64;
  const int bm = blockIdx.x, bn = blockIdx.y;

  const int rseg = lane >> 2;
  const int cofs = ((lane & 3) ^ ((lane >> 3) & 3)) * 8;
  const int sA0 = w, sA1 = w + 4;
  const int arow0 = (bm * 128 + sA0 * 16 + rseg) * K;
  const int arow1 = (bm * 128 + sA1 * 16 + rseg) * K;
  const int brow0 = (bn * 128 + sA0 * 16 + rseg) * K;
  const int brow1 = (bn * 128 + sA1 * 16 + rseg) * K;

  const int rsw = (l15 >> 1) & 3;  // read-side swizzle term

  f32x4 acc[4][4];
#pragma unroll
  for (int i = 0; i < 4; i++)
#pragma unroll
    for (int j = 0; j < 4; j++) acc[i][j] = f32x4{0.f, 0.f, 0.f, 0.f};

  // prologue: stage tiles 0 and 1 into buffers 0 and 1
#pragma unroll
  for (int t = 0; t < 2; t++) {
    gl2lds16(A + arow0 + t * 32 + cofs, &As[t][sA0 * 512]);
    gl2lds16(A + arow1 + t * 32 + cofs, &As[t][sA1 * 512]);
    gl2lds16(Bm + brow0 + t * 32 + cofs, &Bs[t][sA0 * 512]);
    gl2lds16(Bm + brow1 + t * 32 + cofs, &Bs[t][sA1 * 512]);
  }

  const int K32 = K >> 5;
  int cur = 0, pre = 2;  // cur = kt%3, pre = (kt+2)%3
  for (int kt = 0; kt < K32; kt++) {
    // tile kt's 4 staging ops are the oldest outstanding; tile kt+1's 4 may stay in flight
    if (kt < K32 - 1) { asm volatile("s_waitcnt vmcnt(4)" ::: "memory"); }
    else              { asm volatile("s_waitcnt vmcnt(0)" ::: "memory"); }
    __builtin_amdgcn_s_barrier();

    if (kt + 2 < K32) {
      const int k2 = (kt + 2) * 32;
      gl2lds16(A + arow0 + k2 + cofs, &As[pre][sA0 * 512]);
      gl2lds16(A + arow1 + k2 + cofs, &As[pre][sA1 * 512]);
      gl2lds16(Bm + brow0 + k2 + cofs, &Bs[pre][sA0 * 512]);
      gl2lds16(Bm + brow1 + k2 + cofs, &Bs[pre][sA1 * 512]);
    }
    bf16x8 af[4], bf[4];
#pragma unroll
    for (int im = 0; im < 4; im++) af[im] = frag8(&As[cur][(wm + im * 16 + l15) * 32 + (g ^ rsw) * 8]);
#pragma unroll
    for (int jn = 0; jn < 4; jn++) bf[jn] = frag8(&Bs[cur][(wn + jn * 16 + l15) * 32 + (g ^ rsw) * 8]);
#pragma unroll
    for (int im = 0; im < 4; im++)
#pragma unroll
      for (int jn = 0; jn < 4; jn++)
        acc[im][jn] = __builtin_amdgcn_mfma_f32_16x16x32_bf16(af[im], bf[jn], acc[im][jn], 0, 0, 0);

    cur = (cur == 2) ? 0 : cur + 1;
    pre = (pre == 2) ? 0 : pre + 1;
  }

  const int row0 = bm * 128 + wm + g * 4;  // + im*16 + r
  const int col0 = bn * 128 + wn;          // + jn*16 + l15

  if (EPI == 0) {
#pragma unroll
    for (int jn = 0; jn < 4; jn++) {
      float bb = bias[col0 + jn * 16 + l15];
#pragma unroll
      for (int im = 0; im < 4; im++)
#pragma unroll
        for (int r = 0; r < 4; r++) {
          int row = row0 + im * 16 + r;
          Cout[row * N + col0 + jn * 16 + l15] = acc[im][jn][r] + bb;
        }
    }
  } else {
#pragma unroll
    for (int jn = 0; jn < 4; jn++) {
      float bb = bias[col0 + jn * 16 + l15];
#pragma unroll
      for (int im = 0; im < 4; im++)
#pragma unroll
        for (int r = 0; r < 4; r++) acc[im][jn][r] += bb;
    }
    const int sector = col0 >> 10;        // 0=q 1=k 2=v, wave-uniform
    const int h = (col0 & 1023) >> 6;     // wave-uniform head
    if (sector == 2) {
      // V^T scatter, vectorized along pos
#pragma unroll
      for (int jn = 0; jn < 4; jn++) {
        int d = jn * 16 + l15;
#pragma unroll
        for (int im = 0; im < 4; im++) {
          int row = row0 + im * 16;
          int b = row >> 11, pos = row & 2047;
          union { uint32_t u[2]; short4v s4; } pw;
          pw.u[0] = pk2bf(acc[im][jn][0], acc[im][jn][1]);
          pw.u[1] = pk2bf(acc[im][jn][2], acc[im][jn][3]);
          *(short4v*)&Vt[((b * 16 + h) * 64 + d) * 2048 + pos] = pw.s4;
        }
      }
    } else {
      short* dst = (sector == 0) ? Qb : Kb;
      const float scl = (sector == 0) ? 0.18033688011112042f : 1.0f;  // 0.125*log2(e) folded into Q
      const int posb = row0 & 2047;  // b-local pos base for r=0 (block rows never cross a b)
      const int bq = row0 >> 11;     // wave-uniform batch
#pragma unroll
      for (int jn = 0; jn < 4; jn++) {
        int d = jn * 16 + l15;
        int j = d & 31;
        const float* cp = cosT + j * 2048;
        const float* sp = sinT + j * 2048;
#pragma unroll
        for (int im = 0; im < 4; im++) {
          f32x4 cv = *(const f32x4*)(cp + posb + im * 16);
          f32x4 sn = *(const f32x4*)(sp + posb + im * 16);
#pragma unroll
          for (int r = 0; r < 4; r++) {
            int pos = posb + im * 16 + r;
            float xv = acc[im][jn][r];
            float xp = acc[im][jn ^ 2][r];         // partner d +/- 32 lives 2 n-tiles away
            float rot = (jn < 2) ? -xp : xp;       // d<32: -x[d+32]; d>=32: x[d-32]
            dst[((bq * 16 + h) * 2048 + pos) * 64 + d] = f2bf((xv * cv[r] + rot * sn[r]) * scl);
          }
        }
      }
    }
  }
}

// ---------- kernel 4: attention (measured best ~95.6us) ----------
// 256-thread blocks (4 waves), q=128/block (32/wave), kv-tile=32, TRI-buffered staging.
// Grid 1024 (16 qt x 64 bh, XCD-swizzled so XCD k owns bh in [8k,8k+8) -> 4MB K/V = L2-resident).
// 4 blocks/CU at 40KB LDS -> 16 waves/CU.
// Waves 0,1 stage K, waves 2,3 stage V^T; mask in LDS (staged once); loop body issues EXACTLY
// 2 VMEM ops/iter -> counted s_waitcnt vmcnt(2) keeps next tile's loads in flight across the
// raw s_barrier (prefetch distance = 2 iters).
// DEFERRED-PV (T15): iteration t issues PV for tile t-1 from register snapshots (av, bp).
// p = exp2(s + maskf) unnormalized (Q pre-scaled by 0.125*log2e); l via ones-MFMA.
__global__ __launch_bounds__(256, 4)
void attn_k(const short* __restrict__ Qb, const short* __restrict__ Kb,
            const short* __restrict__ Vt, const float* __restrict__ maskf,
            short* __restrict__ attn) {
  __shared__ short Ks[3][32 * 64];  // [kv][d]   rows 128B = 8 chunks, pos = c ^ (row&7)
  __shared__ short Vs[3][64 * 32];  // [d][kv]   rows  64B = 4 chunks, pos = c ^ ((row^(row>>2))&3)
  __shared__ short Ps[4][32 * 32];  // per-wave [q][kv] rows 64B, same 4-chunk swizzle
  __shared__ float Ms[2048];        // this batch's mask row (adds), staged once
  const int tid = threadIdx.x, lane = tid & 63, w = tid >> 6;
  const int g = lane >> 4, l15 = lane & 15;
  const int swk = l15 & 7;                    // Ks read swizzle
  const int fv = (l15 ^ (l15 >> 2)) & 3;      // Vs/Ps read swizzle
  const int swz = (blockIdx.x & 7) * 128 + (blockIdx.x >> 3);
  const int qt = swz & 15, bh = swz >> 4;
  const int b = bh >> 4, h = bh & 15;

  bf16x8 aq[2][2];
#pragma unroll
  for (int qi = 0; qi < 2; qi++)
#pragma unroll
    for (int kc = 0; kc < 2; kc++) {
      int q = qt * 128 + w * 32 + qi * 16 + l15;
      aq[qi][kc] = *(const bf16x8*)(const void*)(Qb + (bh * 2048 + q) * 64 + kc * 32 + g * 8);
    }
  bf16x8 aone;
#pragma unroll
  for (int i = 0; i < 8; i++) aone[i] = (__bf16)1.0f;

  f32x4 o[4][2];
#pragma unroll
  for (int jd = 0; jd < 4; jd++)
#pragma unroll
    for (int qi = 0; qi < 2; qi++) o[jd][qi] = f32x4{0.f, 0.f, 0.f, 0.f};
  f32x4 lacc[2] = {f32x4{0.f, 0.f, 0.f, 0.f}, f32x4{0.f, 0.f, 0.f, 0.f}};

  bf16x8 av[4], bp[2];
#pragma unroll
  for (int jd = 0; jd < 4; jd++)
#pragma unroll
    for (int i = 0; i < 8; i++) av[jd][i] = (__bf16)0.0f;
#pragma unroll
  for (int qi = 0; qi < 2; qi++)
#pragma unroll
    for (int i = 0; i < 8; i++) bp[qi][i] = (__bf16)0.0f;

  const float* mfp = maskf + b * 2048;

  const int kr8 = lane >> 3;
  const int kcst = (lane & 7) ^ kr8;
  const int vrs = lane >> 2;
  const int vcs = (lane & 3) ^ ((vrs ^ (vrs >> 2)) & 3);

#pragma unroll
  for (int i = 0; i < 2; i++) {
    int s = w * 2 + i;
    gl2lds16(mfp + s * 256 + lane * 4, &Ms[s * 256]);
  }
  if (w < 2) {
#pragma unroll
    for (int t = 0; t < 2; t++)
#pragma unroll
      for (int i = 0; i < 2; i++) {
        int s = (w & 1) * 2 + i;
        gl2lds16(Kb + (bh * 2048 + t * 32 + s * 8 + kr8) * 64 + kcst * 8, &Ks[t][s * 512]);
      }
  } else {
#pragma unroll
    for (int t = 0; t < 2; t++)
#pragma unroll
      for (int i = 0; i < 2; i++) {
        int s = (w & 1) * 2 + i;
        gl2lds16(Vt + (bh * 64 + s * 16 + vrs) * 2048 + t * 32 + vcs * 8, &Vs[t][s * 512]);
      }
  }

  int cur = 0, pre = 2;
  for (int kt = 0; kt < 64; kt++) {
    if (kt < 62) {
      asm volatile("s_waitcnt vmcnt(2)" ::: "memory");
    } else {
      asm volatile("s_waitcnt vmcnt(0)" ::: "memory");
    }
    __builtin_amdgcn_s_barrier();

    if (kt < 62) {
      const int nb = (kt + 2) * 32;
      if (w < 2) {
#pragma unroll
        for (int i = 0; i < 2; i++) {
          int s = (w & 1) * 2 + i;
          gl2lds16(Kb + (bh * 2048 + nb + s * 8 + kr8) * 64 + kcst * 8, &Ks[pre][s * 512]);
        }
      } else {
#pragma unroll
        for (int i = 0; i < 2; i++) {
          int s = (w & 1) * 2 + i;
          gl2lds16(Vt + (bh * 64 + s * 16 + vrs) * 2048 + nb + vcs * 8, &Vs[pre][s * 512]);
        }
      }
    }

    __builtin_amdgcn_s_setprio(1);
#pragma unroll
    for (int qi = 0; qi < 2; qi++) {
#pragma unroll
      for (int jd = 0; jd < 4; jd++)
        o[jd][qi] = __builtin_amdgcn_mfma_f32_16x16x32_bf16(av[jd], bp[qi], o[jd][qi], 0, 0, 0);
      lacc[qi] = __builtin_amdgcn_mfma_f32_16x16x32_bf16(aone, bp[qi], lacc[qi], 0, 0, 0);
    }
    __builtin_amdgcn_s_setprio(0);

    const int kbase = kt * 32;
    f32x4 sv[2][2];
#pragma unroll
    for (int kvt = 0; kvt < 2; kvt++) {
      f32x4 mf = *(const f32x4*)(const void*)&Ms[kbase + kvt * 16 + g * 4];
      sv[kvt][0] = mf; sv[kvt][1] = mf;
    }
    __builtin_amdgcn_s_setprio(1);
#pragma unroll
    for (int kvt = 0; kvt < 2; kvt++)
#pragma unroll
      for (int kc = 0; kc < 2; kc++) {
        bf16x8 ak = frag8(&Ks[cur][(kvt * 16 + l15) * 64 + ((kc * 4 + g) ^ swk) * 8]);
        sv[kvt][0] = __builtin_amdgcn_mfma_f32_16x16x32_bf16(ak, aq[0][kc], sv[kvt][0], 0, 0, 0);
        sv[kvt][1] = __builtin_amdgcn_mfma_f32_16x16x32_bf16(ak, aq[1][kc], sv[kvt][1], 0, 0, 0);
      }
    __builtin_amdgcn_s_setprio(0);

#pragma unroll
    for (int jd = 0; jd < 4; jd++)
      av[jd] = frag8(&Vs[cur][(jd * 16 + l15) * 32 + (g ^ fv) * 8]);

#pragma unroll
    for (int qi = 0; qi < 2; qi++)
#pragma unroll
      for (int kvt = 0; kvt < 2; kvt++) {
        union { uint32_t u[2]; short4v s4; } pw;
        pw.u[0] = pk2bf(EXP2(sv[kvt][qi][0]), EXP2(sv[kvt][qi][1]));
        pw.u[1] = pk2bf(EXP2(sv[kvt][qi][2]), EXP2(sv[kvt][qi][3]));
        *(short4v*)&Ps[w][(qi * 16 + l15) * 32 + (((kvt * 2 + (g >> 1)) ^ fv) * 8) + (g & 1) * 4] = pw.s4;
      }
#pragma unroll
    for (int qi = 0; qi < 2; qi++)
      bp[qi] = frag8(&Ps[w][(qi * 16 + l15) * 32 + (g ^ fv) * 8]);

    cur = (cur == 2) ? 0 : cur + 1;
    pre = (pre == 2) ? 0 : pre + 1;
  }

  __builtin_amdgcn_s_setprio(1);
#pragma unroll
  for (int qi = 0; qi < 2; qi++) {
#pragma unroll
    for (int jd = 0; jd < 4; jd++)
      o[jd][qi] = __builtin_amdgcn_mfma_f32_16x16x32_bf16(av[jd], bp[qi], o[jd][qi], 0, 0, 0);
    lacc[qi] = __builtin_amdgcn_mfma_f32_16x16x32_bf16(aone, bp[qi], lacc[qi], 0, 0, 0);
  }
  __builtin_amdgcn_s_setprio(0);

#pragma unroll
  for (int qi = 0; qi < 2; qi++) {
    float inv = 1.0f / lacc[qi][0];
    int q = qt * 128 + w * 32 + qi * 16 + l15;
#pragma unroll
    for (int jd = 0; jd < 4; jd++) {
      union { uint32_t u[2]; short4v s4; } pw;
      pw.u[0] = pk2bf(o[jd][qi][0] * inv, o[jd][qi][1] * inv);
      pw.u[1] = pk2bf(o[jd][qi][2] * inv, o[jd][qi][3] * inv);
      *(short4v*)&attn[(b * 2048 + q) * 1024 + h * 64 + jd * 16 + g * 4] = pw.s4;
    }
  }
}

// ---------- launch ----------
extern "C" void kernel_launch(void* const* d_in, const int* in_sizes, int n_in,
                              void* d_out, int out_size, void* d_ws, size_t ws_size,
                              hipStream_t stream) {
  const float* x = (const float*)d_in[0];
  const unsigned char* mask = (const unsigned char*)d_in[1];
  const float* W_qkv = (const float*)d_in[2];
  const float* b_qkv = (const float*)d_in[3];
  const float* W_out = (const float*)d_in[4];
  const float* b_out = (const float*)d_in[5];
  float* out = (float*)d_out;

  char* ws = (char*)d_ws;
  short* xb    = (short*)(ws + 0);          // 16,777,216 B
  short* wqkvb = (short*)(ws + 16777216);   //  6,291,456 B
  short* woutb = (short*)(ws + 23068672);   //  2,097,152 B
  float* cosT  = (float*)(ws + 25165824);   //    262,144 B  [j=32][pos=2048]
  float* sinT  = (float*)(ws + 25427968);   //    262,144 B  [j=32][pos=2048]
  short* Qb    = (short*)(ws + 25690112);   // 16,777,216 B  [bh][pos][64]
  short* Kb    = (short*)(ws + 42467328);   // 16,777,216 B  [bh][pos][64]
  short* Vtb   = (short*)(ws + 59244544);   // 16,777,216 B  [bh][64][pos]
  short* attnb = (short*)(ws + 76021760);   // 16,777,216 B  [B,L,D] bf16
  float* maskf = (float*)(ws + 92798976);   //     32,768 B

  // 12288 convert blocks + 256 rope/mask blocks fused into one launch
  convert3_k<<<12544, 256, 0, stream>>>(x, xb, 8388608, W_qkv, wqkvb, 3145728,
                                        W_out, woutb, 1048576,
                                        cosT, sinT, mask, maskf);
  gemm_bt_k<1><<<dim3(64, 24), 256, 0, stream>>>(xb, wqkvb, b_qkv, 3072, 1024,
                                                 nullptr, cosT, sinT, Qb, Kb, Vtb);
  attn_k<<<dim3(1024), 256, 0, stream>>>(Qb, Kb, Vtb, maskf, attnb);
  gemm_bt_k<0><<<dim3(64, 8), 256, 0, stream>>>(attnb, woutb, b_out, 1024, 1024,
                                                out, nullptr, nullptr, nullptr, nullptr, nullptr);
}